// Round 1
// baseline (409.832 us; speedup 1.0000x reference)
//
#include <hip/hip_runtime.h>

// EdgeAttention: 4-scale 1x1-conv projection + pairwise per-pixel cosine + 4x4 softmax.
// Scales: L = {6400,1600,400,100} at 80/40/20/10; nearest upsample == block replication
// (src = dst >> d), so pair (i,j) cosine mean reduces to a mean over the finer grid.
// Diagonal attn == 1 exactly.

#define CCH 256

// ---------------- Projection GEMM: P[b,o,l] = sum_c W[o,c] * F[b,c,l] + bias[o] ----------
// fp32, 64x64 tile, 16x16 threads, 4x4 micro-tile.
__global__ void proj_gemm(const float* __restrict__ F, const float* __restrict__ Wm,
                          const float* __restrict__ bias, float* __restrict__ P, int L) {
    __shared__ float Ws[16][65];   // Ws[k][o]
    __shared__ float Fs[16][65];   // Fs[k][l]
    const int tx = threadIdx.x, ty = threadIdx.y;
    const int tid = ty * 16 + tx;
    const int bl = blockIdx.x * 64;
    const int bo = blockIdx.y * 64;
    const int b  = blockIdx.z;
    const float* Fb = F + (size_t)b * CCH * L;

    float acc[4][4] = {};

    for (int k0 = 0; k0 < CCH; k0 += 16) {
        // W tile: Ws[k][o] = Wm[(bo+o)*C + k0+k]; k fastest per tid for 64B segments.
#pragma unroll
        for (int p = 0; p < 4; ++p) {
            int idx = p * 256 + tid;
            int k = idx & 15;
            int o = idx >> 4;
            Ws[k][o] = Wm[(size_t)(bo + o) * CCH + k0 + k];
        }
        // F tile: Fs[k][l] = Fb[(k0+k)*L + bl+l]; l fastest -> fully coalesced.
#pragma unroll
        for (int p = 0; p < 4; ++p) {
            int idx = p * 256 + tid;
            int l = idx & 63;
            int k = idx >> 6;
            int gl = bl + l;
            Fs[k][l] = (gl < L) ? Fb[(size_t)(k0 + k) * L + gl] : 0.f;
        }
        __syncthreads();
#pragma unroll
        for (int k = 0; k < 16; ++k) {
            float av[4], bv[4];
#pragma unroll
            for (int i = 0; i < 4; ++i) av[i] = Ws[k][ty * 4 + i];
#pragma unroll
            for (int j = 0; j < 4; ++j) bv[j] = Fs[k][tx * 4 + j];
#pragma unroll
            for (int i = 0; i < 4; ++i)
#pragma unroll
                for (int j = 0; j < 4; ++j)
                    acc[i][j] += av[i] * bv[j];
        }
        __syncthreads();
    }

#pragma unroll
    for (int i = 0; i < 4; ++i) {
        int o = bo + ty * 4 + i;
        float bvv = bias[o];
#pragma unroll
        for (int j = 0; j < 4; ++j) {
            int gl = bl + tx * 4 + j;
            if (gl < L)
                P[((size_t)b * CCH + o) * L + gl] = acc[i][j] + bvv;
        }
    }
}

// ---------------- Pair cosine accumulation (norms fused) ----------------
// For pair (i,j), i<j: mean over grid_i pixels of cos(p_i[l], p_j[l>>d]).
// Accumulates sum of cosines into sums[b*6 + pair] via one atomic per block.
__global__ void pair_cos(const float* __restrict__ p0, const float* __restrict__ p1,
                         const float* __restrict__ p2, const float* __restrict__ p3,
                         float* __restrict__ sums) {
    const int pair = blockIdx.y;
    const int b = blockIdx.z;
    int i, j;
    switch (pair) {
        case 0: i = 0; j = 1; break;
        case 1: i = 0; j = 2; break;
        case 2: i = 0; j = 3; break;
        case 3: i = 1; j = 2; break;
        case 4: i = 1; j = 3; break;
        default: i = 2; j = 3; break;
    }
    const float* P[4] = {p0, p1, p2, p3};
    const float* pi = P[i];
    const float* pj = P[j];
    const int ri = 80 >> i, rj = 80 >> j;
    const int Li = ri * ri, Lj = rj * rj;

    int pix = blockIdx.x * 256 + threadIdx.x;
    float cosv = 0.f;
    if (pix < Li) {
        int h = pix / ri, w = pix - h * ri;
        int d = j - i;
        int l2 = (h >> d) * rj + (w >> d);
        const float* a  = pi + (size_t)b * CCH * Li + pix;
        const float* bb = pj + (size_t)b * CCH * Lj + l2;
        float dot = 0.f, nii = 0.f, njj = 0.f;
        for (int c = 0; c < CCH; ++c) {
            float x = a[(size_t)c * Li];
            float y = bb[(size_t)c * Lj];
            dot += x * y;
            nii += x * x;
            njj += y * y;
        }
        cosv = dot / fmaxf(sqrtf(nii) * sqrtf(njj), 1e-8f);
    }

    __shared__ float red[256];
    red[threadIdx.x] = cosv;
    __syncthreads();
    for (int s = 128; s > 0; s >>= 1) {
        if (threadIdx.x < s) red[threadIdx.x] += red[threadIdx.x + s];
        __syncthreads();
    }
    if (threadIdx.x == 0) atomicAdd(&sums[b * 6 + pair], red[0]);
}

// ---------------- Softmax over j for each (b,i) row ----------------
__global__ void softmax4(const float* __restrict__ sums, float* __restrict__ out) {
    int t = threadIdx.x;
    if (t >= 128) return;
    int b = t >> 4, i = (t >> 2) & 3, j = t & 3;
    float a[4];
#pragma unroll
    for (int jj = 0; jj < 4; ++jj) {
        if (jj == i) {
            a[jj] = 1.0f;
        } else {
            int lo = i < jj ? i : jj;
            int hi = i < jj ? jj : i;
            int pidx;
            if (lo == 0) pidx = hi - 1;          // (0,1)=0 (0,2)=1 (0,3)=2
            else if (lo == 1) pidx = 1 + hi;     // (1,2)=3 (1,3)=4
            else pidx = 5;                       // (2,3)=5
            int rf = 80 >> lo;
            a[jj] = sums[b * 6 + pidx] / (float)(rf * rf);
        }
    }
    float m = fmaxf(fmaxf(a[0], a[1]), fmaxf(a[2], a[3]));
    float e0 = expf(a[0] - m), e1 = expf(a[1] - m), e2 = expf(a[2] - m), e3 = expf(a[3] - m);
    float s = e0 + e1 + e2 + e3;
    float ev = (j == 0) ? e0 : (j == 1) ? e1 : (j == 2) ? e2 : e3;
    out[t] = ev / s;
}

extern "C" void kernel_launch(void* const* d_in, const int* in_sizes, int n_in,
                              void* d_out, int out_size, void* d_ws, size_t ws_size,
                              hipStream_t stream) {
    // setup_inputs dict order (interleaved): f0,w0,b0, f1,w1,b1, f2,w2,b2, f3,w3,b3
    const float* f[4]  = {(const float*)d_in[0], (const float*)d_in[3],
                          (const float*)d_in[6], (const float*)d_in[9]};
    const float* w[4]  = {(const float*)d_in[1], (const float*)d_in[4],
                          (const float*)d_in[7], (const float*)d_in[10]};
    const float* bs[4] = {(const float*)d_in[2], (const float*)d_in[5],
                          (const float*)d_in[8], (const float*)d_in[11]};

    const int Ls[4] = {6400, 1600, 400, 100};
    float* ws = (float*)d_ws;
    size_t off = 0;
    float* p[4];
    for (int s = 0; s < 4; ++s) { p[s] = ws + off; off += (size_t)8 * CCH * Ls[s]; }
    float* sums = ws + off;   // 48 floats used

    hipMemsetAsync(sums, 0, 64 * sizeof(float), stream);

    for (int s = 0; s < 4; ++s) {
        dim3 grid((Ls[s] + 63) / 64, 4, 8);
        proj_gemm<<<grid, dim3(16, 16), 0, stream>>>(f[s], w[s], bs[s], p[s], Ls[s]);
    }

    pair_cos<<<dim3(25, 6, 8), 256, 0, stream>>>(p[0], p[1], p[2], p[3], sums);

    softmax4<<<1, 128, 0, stream>>>(sums, (float*)d_out);
}

// Round 3
// 177.821 us; speedup vs baseline: 2.3047x; 2.3047x over previous
//
#include <hip/hip_runtime.h>

// EdgeAttention: 4-scale 1x1-conv projection + pairwise per-pixel cosine + 4x4 softmax.
// Round 3: fix round-2 bug — epilogue computed the 1/|p| factor but never applied it.
// Structure: bf16 MFMA fused proj+bias+L2-normalize -> unit vectors (bf16) -> pure-dot
// pair pass -> tiny softmax. Nearest upsample == block replication (src = dst >> d), so
// the pair (i,j) mean is over the finer grid. Diagonal attn == 1 exactly.

#define CCH 256

typedef __attribute__((ext_vector_type(8))) short short8;
typedef __attribute__((ext_vector_type(4))) float float4_;

__device__ inline short f2bf(float x) {   // round-to-nearest-even fp32 -> bf16
    union { float f; unsigned u; } c; c.f = x;
    unsigned u = c.u + 0x7FFFu + ((c.u >> 16) & 1u);
    return (short)(u >> 16);
}
__device__ inline float bf2f(short b) {
    union { unsigned u; float f; } c; c.u = ((unsigned)(unsigned short)b) << 16;
    return c.f;
}

// ---------- W pack: fp32 [o][c] -> bf16 [ks][o][kk] (ks = c/32, kk = c%32) ----------
__global__ void pack_w(const float* __restrict__ w0, const float* __restrict__ w1,
                       const float* __restrict__ w2, const float* __restrict__ w3,
                       short* __restrict__ wp) {
    const float* W[4] = {w0, w1, w2, w3};
    const float* Ws = W[blockIdx.y];
    short* out = wp + (size_t)blockIdx.y * 65536;
    int base = (blockIdx.x * 256 + threadIdx.x) * 8;   // grid.x=32 -> 65536 shorts
    int kk0 = base & 31;
    int o   = (base >> 5) & 255;
    int ks  = base >> 13;
    const float* src = Ws + o * CCH + ks * 32 + kk0;
    short8 v;
#pragma unroll
    for (int j = 0; j < 8; ++j) v[j] = f2bf(src[j]);
    *(short8*)(out + base) = v;
}

// ---------- Fused projection GEMM (bf16 MFMA) + bias + L2-normalize ----------
// Block = 256 thr = 4 waves; computes all 256 out-channels for 64 pixels of one (scale,b).
// Wave w owns pixels [tile*64 + w*16, +16). A=W (16 M-tiles), B=F (16 pixels), K=256.
#define LDP 56   // LDS row pitch in shorts: 112 B = 16B-aligned, 2-way bank alias (free)
__global__ __launch_bounds__(256) void proj_norm(
    const float* __restrict__ f0, const float* __restrict__ f1,
    const float* __restrict__ f2, const float* __restrict__ f3,
    const short* __restrict__ wp,
    const float* __restrict__ b0, const float* __restrict__ b1,
    const float* __restrict__ b2, const float* __restrict__ b3,
    short* __restrict__ u0, short* __restrict__ u1,
    short* __restrict__ u2, short* __restrict__ u3)
{
    __shared__ short Wt[256 * LDP];   // 28 KB
    __shared__ short Ft[64 * LDP];    // 7 KB
    __shared__ float biasS[256];

    const int blk = blockIdx.x;
    int s, b, tile, L;
    const float* F; const float* bias; short* U;
    if (blk < 800)       { s = 0; int r = blk;        b = r / 100; tile = r % 100; L = 6400; F = f0; bias = b0; U = u0; }
    else if (blk < 1000) { s = 1; int r = blk - 800;  b = r / 25;  tile = r % 25;  L = 1600; F = f1; bias = b1; U = u1; }
    else if (blk < 1056) { s = 2; int r = blk - 1000; b = r / 7;   tile = r % 7;   L = 400;  F = f2; bias = b2; U = u2; }
    else                 { s = 3; int r = blk - 1056; b = r / 2;   tile = r % 2;   L = 100;  F = f3; bias = b3; U = u3; }

    const int t    = threadIdx.x;
    const int lane = t & 63;
    const int wav  = t >> 6;
    const int ln   = lane & 15;
    const int quad = lane >> 4;
    const int pixbase = tile * 64;
    const float* Fb = F + (size_t)b * CCH * L;
    const short* wbase = wp + (size_t)s * 65536;

    biasS[t] = bias[t];

    float4_ acc[16];
#pragma unroll
    for (int i = 0; i < 16; ++i) acc[i] = (float4_){0.f, 0.f, 0.f, 0.f};

    // F staging: thread loads 8 channels (fk0..fk0+7) of its pixel, packs one short8.
    const int fpix = t & 63;
    const int fk0  = (t >> 6) * 8;
    const int gpix = pixbase + fpix;
    const bool pin = gpix < L;

    for (int ks = 0; ks < 8; ++ks) {
        __syncthreads();
        // W slice: contiguous 16 KB copy (pre-packed), LDS rows [o][kk] padded to LDP.
        {
            const short8* src = (const short8*)(wbase + ks * 8192);
#pragma unroll
            for (int it = 0; it < 4; ++it) {
                int idx = it * 256 + t;
                short8 v = src[idx];
                *(short8*)(&Wt[(idx >> 2) * LDP + (idx & 3) * 8]) = v;
            }
        }
        // F slice: [pixel][kk] rows (B-fragment layout), fp32->bf16 on the fly.
        {
            const float* fs = Fb + (size_t)(ks * 32 + fk0) * L + gpix;
            short8 v;
#pragma unroll
            for (int j = 0; j < 8; ++j)
                v[j] = f2bf(pin ? fs[(size_t)j * L] : 0.f);
            *(short8*)(&Ft[fpix * LDP + fk0]) = v;
        }
        __syncthreads();
        short8 bfrag = *(const short8*)(&Ft[(wav * 16 + ln) * LDP + quad * 8]);
#pragma unroll
        for (int mt = 0; mt < 16; ++mt) {
            short8 afrag = *(const short8*)(&Wt[(mt * 16 + ln) * LDP + quad * 8]);
            acc[mt] = __builtin_amdgcn_mfma_f32_16x16x32_bf16(afrag, bfrag, acc[mt], 0, 0, 0);
        }
    }

    // Epilogue: bias, per-pixel norm (4 quads hold 64 channels each), normalize, store bf16.
    // C/D layout (16x16x32): col(pixel) = lane&15, row(channel) = quad*4 + reg.
    const int mygp = pixbase + wav * 16 + ln;
    float ss = 0.f;
#pragma unroll
    for (int mt = 0; mt < 16; ++mt) {
#pragma unroll
        for (int r = 0; r < 4; ++r) {
            float v = acc[mt][r] + biasS[mt * 16 + quad * 4 + r];
            acc[mt][r] = v;
            ss += v * v;
        }
    }
    ss += __shfl_xor(ss, 16);
    ss += __shfl_xor(ss, 32);
    const float inv = 1.f / sqrtf(fmaxf(ss, 1e-24f));
    if (mygp < L) {
        short* Ub = U + (size_t)b * CCH * L + mygp;
#pragma unroll
        for (int mt = 0; mt < 16; ++mt) {
#pragma unroll
            for (int r = 0; r < 4; ++r)
                Ub[(size_t)(mt * 16 + quad * 4 + r) * L] = f2bf(acc[mt][r] * inv);
        }
    }
}

// ---------- Pair dot (unit vectors): partial per block, no atomics ----------
__global__ void pair_cos(const short* __restrict__ u0, const short* __restrict__ u1,
                         const short* __restrict__ u2, const short* __restrict__ u3,
                         float* __restrict__ partial) {
    const int pair = blockIdx.y;
    const int b = blockIdx.z;
    int i, j;
    switch (pair) {
        case 0: i = 0; j = 1; break;
        case 1: i = 0; j = 2; break;
        case 2: i = 0; j = 3; break;
        case 3: i = 1; j = 2; break;
        case 4: i = 1; j = 3; break;
        default: i = 2; j = 3; break;
    }
    const short* P[4] = {u0, u1, u2, u3};
    const short* pi = P[i];
    const short* pj = P[j];
    const int ri = 80 >> i, rj = 80 >> j;
    const int Li = ri * ri, Lj = rj * rj;

    int pix = blockIdx.x * 256 + threadIdx.x;
    float dot = 0.f;
    if (pix < Li) {
        int h = pix / ri, w = pix - h * ri;
        int d = j - i;
        int l2 = (h >> d) * rj + (w >> d);
        const short* a  = pi + (size_t)b * CCH * Li + pix;
        const short* bb = pj + (size_t)b * CCH * Lj + l2;
#pragma unroll 4
        for (int c = 0; c < CCH; ++c)
            dot += bf2f(a[(size_t)c * Li]) * bf2f(bb[(size_t)c * Lj]);
    }

    __shared__ float red[256];
    red[threadIdx.x] = dot;
    __syncthreads();
    for (int s2 = 128; s2 > 0; s2 >>= 1) {
        if (threadIdx.x < s2) red[threadIdx.x] += red[threadIdx.x + s2];
        __syncthreads();
    }
    if (threadIdx.x == 0) partial[(b * 6 + pair) * 25 + blockIdx.x] = red[0];
}

// ---------- Softmax over j for each (b,i) row ----------
__global__ void softmax4(const float* __restrict__ partial, float* __restrict__ out) {
    int t = threadIdx.x;
    if (t >= 128) return;
    int b = t >> 4, i = (t >> 2) & 3, j = t & 3;
    float a[4];
#pragma unroll
    for (int jj = 0; jj < 4; ++jj) {
        if (jj == i) { a[jj] = 1.0f; continue; }
        int lo = i < jj ? i : jj;
        int hi = i < jj ? jj : i;
        int pidx;
        if (lo == 0) pidx = hi - 1;          // (0,1)=0 (0,2)=1 (0,3)=2
        else if (lo == 1) pidx = 1 + hi;     // (1,2)=3 (1,3)=4
        else pidx = 5;                       // (2,3)=5
        float s = 0.f;
        for (int k = 0; k < 25; ++k) s += partial[(b * 6 + pidx) * 25 + k];
        int rf = 80 >> lo;
        a[jj] = s / (float)(rf * rf);
    }
    float m = fmaxf(fmaxf(a[0], a[1]), fmaxf(a[2], a[3]));
    float e0 = expf(a[0] - m), e1 = expf(a[1] - m), e2 = expf(a[2] - m), e3 = expf(a[3] - m);
    float sum = e0 + e1 + e2 + e3;
    float ev = (j == 0) ? e0 : (j == 1) ? e1 : (j == 2) ? e2 : e3;
    out[t] = ev / sum;
}

extern "C" void kernel_launch(void* const* d_in, const int* in_sizes, int n_in,
                              void* d_out, int out_size, void* d_ws, size_t ws_size,
                              hipStream_t stream) {
    // setup_inputs dict insertion order: f0,w0,b0, f1,w1,b1, f2,w2,b2, f3,w3,b3
    const float* f[4]  = {(const float*)d_in[0], (const float*)d_in[3],
                          (const float*)d_in[6], (const float*)d_in[9]};
    const float* w[4]  = {(const float*)d_in[1], (const float*)d_in[4],
                          (const float*)d_in[7], (const float*)d_in[10]};
    const float* bs[4] = {(const float*)d_in[2], (const float*)d_in[5],
                          (const float*)d_in[8], (const float*)d_in[11]};

    const int Ls[4] = {6400, 1600, 400, 100};
    char* ws = (char*)d_ws;
    size_t off = 0;
    short* u[4];
    for (int s = 0; s < 4; ++s) {
        u[s] = (short*)(ws + off);
        off += (size_t)8 * CCH * Ls[s] * sizeof(short);
    }
    short* wp = (short*)(ws + off); off += 4 * 65536 * sizeof(short);
    float* partial = (float*)(ws + off);   // 8*6*25 floats

    pack_w<<<dim3(32, 4), 256, 0, stream>>>(w[0], w[1], w[2], w[3], wp);

    proj_norm<<<1072, 256, 0, stream>>>(f[0], f[1], f[2], f[3], wp,
                                        bs[0], bs[1], bs[2], bs[3],
                                        u[0], u[1], u[2], u[3]);

    pair_cos<<<dim3(25, 6, 8), 256, 0, stream>>>(u[0], u[1], u[2], u[3], partial);

    softmax4<<<1, 128, 0, stream>>>(partial, (float*)d_out);
}